// Round 1
// baseline (576.731 us; speedup 1.0000x reference)
//
#include <hip/hip_runtime.h>

#define NN 128
#define NITER 300
#define NROUND 4   // bracket /5^4 = /625 (tau0 err ~<2e-3), then TWO exact
                   // active-set Newton steps (was: 5 rounds + 1 step). The 2nd
                   // Newton re-derives the active set at tauf1, so typical tau
                   // is EXACT -> accuracy >= old scheme, ~100cyc/iter cheaper.

typedef __attribute__((ext_vector_type(2))) float v2f;

// ---- packed-f32 VOP3P helpers (v_pk_* are full-rate on gfx90a+/gfx950) ----
// The scalar operand is an SGPR PAIR packed from two readlane results; the
// pack is SALU (parallel pipe) or free (REG_SEQUENCE), so 1 pk_fma replaces
// 2 v_fma with no duplication movs.
__device__ __forceinline__ long long pack_ss(float lo, float hi) {
  return (long long)(((unsigned long long)(unsigned)__float_as_int(hi) << 32)
                   | (unsigned long long)(unsigned)__float_as_int(lo));
}
__device__ __forceinline__ void pk_fma_s(v2f& acc, v2f a, long long b) {
  asm("v_pk_fma_f32 %0, %1, %2, %0" : "+v"(acc) : "v"(a), "s"(b));
}
__device__ __forceinline__ void pk_fma_v(v2f& acc, v2f a, v2f b) {
  asm("v_pk_fma_f32 %0, %1, %2, %0" : "+v"(acc) : "v"(a), "v"(b));
}
__device__ __forceinline__ v2f pk_mul_s(v2f a, long long b) {
  v2f d; asm("v_pk_mul_f32 %0, %1, %2" : "=v"(d) : "v"(a), "s"(b)); return d;
}

// ---- DPP wave-64 cross-lane helpers (unchanged, R5-proven) ----
template<int CTRL>
__device__ __forceinline__ float dpp0(float x) {  // invalid lanes contribute 0
  return __int_as_float(__builtin_amdgcn_update_dpp(0, __float_as_int(x), CTRL, 0xF, 0xF, true));
}
template<int CTRL>
__device__ __forceinline__ float dppS(float x) {  // invalid lanes keep self
  int xi = __float_as_int(x);
  return __int_as_float(__builtin_amdgcn_update_dpp(xi, xi, CTRL, 0xF, 0xF, false));
}
__device__ __forceinline__ float bcast63(float x) {
  return __int_as_float(__builtin_amdgcn_readlane(__float_as_int(x), 63));
}
__device__ __forceinline__ float rlane(float x, int l) {   // l literal after unroll
  return __int_as_float(__builtin_amdgcn_readlane(__float_as_int(x), l));
}
__device__ __forceinline__ float wsum(float x) {
  x += dpp0<0x111>(x); x += dpp0<0x112>(x); x += dpp0<0x114>(x);
  x += dpp0<0x118>(x); x += dpp0<0x142>(x); x += dpp0<0x143>(x);
  return bcast63(x);
}
__device__ __forceinline__ void wsum2(float& x, float& y) {  // two interleaved chains
  float a = x, b = y;
  a += dpp0<0x111>(a); b += dpp0<0x111>(b);
  a += dpp0<0x112>(a); b += dpp0<0x112>(b);
  a += dpp0<0x114>(a); b += dpp0<0x114>(b);
  a += dpp0<0x118>(a); b += dpp0<0x118>(b);
  a += dpp0<0x142>(a); b += dpp0<0x142>(b);
  a += dpp0<0x143>(a); b += dpp0<0x143>(b);
  x = bcast63(a); y = bcast63(b);
}
__device__ __forceinline__ void wsum4(float& a, float& b, float& c, float& d) {
  a += dpp0<0x111>(a); b += dpp0<0x111>(b); c += dpp0<0x111>(c); d += dpp0<0x111>(d);
  a += dpp0<0x112>(a); b += dpp0<0x112>(b); c += dpp0<0x112>(c); d += dpp0<0x112>(d);
  a += dpp0<0x114>(a); b += dpp0<0x114>(b); c += dpp0<0x114>(c); d += dpp0<0x114>(d);
  a += dpp0<0x118>(a); b += dpp0<0x118>(b); c += dpp0<0x118>(c); d += dpp0<0x118>(d);
  a += dpp0<0x142>(a); b += dpp0<0x142>(b); c += dpp0<0x142>(c); d += dpp0<0x142>(d);
  a += dpp0<0x143>(a); b += dpp0<0x143>(b); c += dpp0<0x143>(c); d += dpp0<0x143>(d);
  a = bcast63(a); b = bcast63(b); c = bcast63(c); d = bcast63(d);
}
__device__ __forceinline__ void wminmax(float& mn, float& mx) {  // interleaved
  mn = fminf(mn, dppS<0x111>(mn)); mx = fmaxf(mx, dppS<0x111>(mx));
  mn = fminf(mn, dppS<0x112>(mn)); mx = fmaxf(mx, dppS<0x112>(mx));
  mn = fminf(mn, dppS<0x114>(mn)); mx = fmaxf(mx, dppS<0x114>(mx));
  mn = fminf(mn, dppS<0x118>(mn)); mx = fmaxf(mx, dppS<0x118>(mx));
  mn = fminf(mn, dppS<0x142>(mn)); mx = fmaxf(mx, dppS<0x142>(mx));
  mn = fminf(mn, dppS<0x143>(mn)); mx = fmaxf(mx, dppS<0x143>(mx));
  mn = bcast63(mn); mx = bcast63(mx);
}

// ONE WAVE PER SAMPLE. PAIR LAYOUT: lane owns coords/rows {2*lane, 2*lane+1}
// so packed-f32 operands pair naturally along columns {2j, 2j+1}.
__launch_bounds__(64, 1)
__global__ void markowitz_kernel(const float* __restrict__ rets,
                                 const float* __restrict__ cov,
                                 const float* __restrict__ gam,
                                 const float* __restrict__ alp,
                                 float* __restrict__ out)
{
  const int b    = blockIdx.x;
  const int lane = threadIdx.x;          // block = exactly one wave (64)

  const float g   = gam[b];
  const float g2  = g * g;
  const float aab = fabsf(alp[b]);
  const v2f* cb2 = (const v2f*)(cov + (size_t)b * (NN * NN));

  // ---------- build Q = g2*C^T C + aab*I (rows 2l, 2l+1; column pairs) ------
  // qA[j] = {Q[2l][2j], Q[2l][2j+1]} / g2 (pre-scale), qB = row 2l+1
  v2f qA[64], qB[64];
  #pragma unroll
  for (int j = 0; j < 64; ++j) { v2f z = {0.f, 0.f}; qA[j] = z; qB[j] = z; }

  // 2-row-deep prefetch: inner body ~520cyc < ~900cyc HBM latency, so 1-ahead
  // (old unroll-2) would stall now that pk halves the body.
  v2f c0 = cb2[lane];
  v2f c1 = cb2[64 + lane];
  #pragma unroll 2
  for (int k = 0; k < NN; ++k) {
    v2f c = c0; c0 = c1;
    int kp = (k + 2 < NN) ? (k + 2) : (NN - 1);
    c1 = cb2[(size_t)kp * 64 + lane];
    v2f cxx = { c.x, c.x }, cyy = { c.y, c.y };
    #pragma unroll
    for (int j = 0; j < 64; ++j) {
      // {C[k][2j], C[k][2j+1]} as an SGPR pair, shared by both row-FMAs
      long long sp = pack_ss(rlane(c.x, j), rlane(c.y, j));
      pk_fma_s(qA[j], cxx, sp);       // Q[2l][2j..2j+1]   += C[k][2l]  *{..}
      pk_fma_s(qB[j], cyy, sp);       // Q[2l+1][2j..2j+1] += C[k][2l+1]*{..}
    }
  }

  // scale by g2, diagonal, Frobenius^2 (4 packed partial chains)
  const long long g2p = pack_ss(g2, g2);
  v2f f0 = {0.f,0.f}, f1 = {0.f,0.f}, f2 = {0.f,0.f}, f3 = {0.f,0.f};
  #pragma unroll
  for (int j = 0; j < 64; ++j) {
    v2f qa = pk_mul_s(qA[j], g2p);
    v2f qb = pk_mul_s(qB[j], g2p);
    if (j == lane) { qa.x += aab; qb.y += aab; }   // diag: col 2l -> pair l .x, col 2l+1 -> .y
    qA[j] = qa; qB[j] = qb;
    if (j & 1) { pk_fma_v(f0, qa, qa); pk_fma_v(f1, qb, qb); }
    else       { pk_fma_v(f2, qa, qa); pk_fma_v(f3, qb, qb); }
  }
  const float S    = wsum(((f0.x + f2.x) + (f0.y + f2.y)) + ((f1.x + f3.x) + (f1.y + f3.y)));
  const float step = 0.5f / sqrtf(S);    // 1/(2||Q||_F)
  const float sc   = 2.f * step;
  const long long scp = pack_ss(sc, sc);
  #pragma unroll
  for (int j = 0; j < 64; ++j) { qA[j] = pk_mul_s(qA[j], scp); qB[j] = pk_mul_s(qB[j], scp); }

  v2f rr = ((const v2f*)rets)[(size_t)b * 64 + lane];
  const float r2e = step * rr.x;
  const float r2o = step * rr.y;

  // ---------- FISTA, fully in-wave ----------
  float ye = 1.f / 128.f, yo = 1.f / 128.f;   // y coords (2l, 2l+1)
  float wpe = ye, wpo = yo;                   // w_prev
  float t_f = 1.f;

  #pragma unroll 1
  for (int it = 0; it < NITER; ++it) {
    // matvec: 128 rlane + 128 pk_fma (was 128 rlane + 256 fma); 4 acc chains
    v2f sA0 = {0.f,0.f}, sA1 = {0.f,0.f}, sB0 = {0.f,0.f}, sB1 = {0.f,0.f};
    #pragma unroll
    for (int j = 0; j < 64; j += 2) {
      long long p0 = pack_ss(rlane(ye, j),     rlane(yo, j));     // {y[2j],y[2j+1]}
      long long p1 = pack_ss(rlane(ye, j + 1), rlane(yo, j + 1));
      pk_fma_s(sA0, qA[j],     p0);
      pk_fma_s(sB0, qB[j],     p0);
      pk_fma_s(sA1, qA[j + 1], p1);
      pk_fma_s(sB1, qB[j + 1], p1);
    }
    float v0 = ye - ((sA0.x + sA0.y) + (sA1.x + sA1.y)) + r2e;   // v = y - step*grad
    float v1 = yo - ((sB0.x + sB0.y) + (sB1.x + sB1.y)) + r2o;

    // projection onto {sum w=1, 0<=w<=1}: 4 rounds x 4-point bracket search
    float mn = fminf(v0, v1), mx = fmaxf(v0, v1);
    wminmax(mn, mx);
    float lo = mn - 1.0f;
    float W  = mx - lo;
    #pragma unroll 1
    for (int r = 0; r < NROUND; ++r) {
      float h  = W * 0.2f;
      float t1v = lo + h, t2v = lo + 2.f*h, t3v = lo + 3.f*h, t4v = lo + 4.f*h;
      float s1 = __builtin_amdgcn_fmed3f(v0 - t1v, 0.f, 1.f)
               + __builtin_amdgcn_fmed3f(v1 - t1v, 0.f, 1.f);
      float s2 = __builtin_amdgcn_fmed3f(v0 - t2v, 0.f, 1.f)
               + __builtin_amdgcn_fmed3f(v1 - t2v, 0.f, 1.f);
      float s3 = __builtin_amdgcn_fmed3f(v0 - t3v, 0.f, 1.f)
               + __builtin_amdgcn_fmed3f(v1 - t3v, 0.f, 1.f);
      float s4 = __builtin_amdgcn_fmed3f(v0 - t4v, 0.f, 1.f)
               + __builtin_amdgcn_fmed3f(v1 - t4v, 0.f, 1.f);
      wsum4(s1, s2, s3, s4);
      // s monotone decreasing in tau: cnt = #points with s>1 selects sub-interval
      float cnt = ((s1 > 1.f ? 1.f : 0.f) + (s2 > 1.f ? 1.f : 0.f))
                + ((s3 > 1.f ? 1.f : 0.f) + (s4 > 1.f ? 1.f : 0.f));
      lo = fmaf(cnt, h, lo);
      W  = h;
    }
    float tauf = lo + 0.5f * W;

    // two exact active-set Newton steps; second one also produces w
    float w0 = 0.f, w1 = 0.f;
    #pragma unroll
    for (int e = 0; e < 2; ++e) {
      float z0 = v0 - tauf, z1 = v1 - tauf;
      bool fr0 = (z0 > 0.f) && (z0 < 1.0f);
      bool fr1 = (z1 > 0.f) && (z1 < 1.0f);
      bool cp0 = (z0 >= 1.0f), cp1 = (z1 >= 1.0f);
      float sfv = (fr0 ? v0 : 0.f) + (fr1 ? v1 : 0.f);
      float cnt = (fr0 ? 1.f : 0.f) + (fr1 ? 1.f : 0.f)
                + 1024.f * ((cp0 ? 1.f : 0.f) + (cp1 ? 1.f : 0.f));
      wsum2(sfv, cnt);
      float nu    = floorf(cnt * (1.f / 1024.f));
      float nfree = fmaxf(cnt - 1024.f * nu, 1.f);
      tauf = (sfv + nu - 1.f) * __builtin_amdgcn_rcpf(nfree);  // exact tau on fixed set
      if (e == 1) {
        w0 = fr0 ? (v0 - tauf) : (cp0 ? 1.0f : 0.f);
        w1 = fr1 ? (v1 - tauf) : (cp1 ? 1.0f : 0.f);
      }
    }

    // FISTA momentum
    float tn   = 0.5f * (1.f + sqrtf(1.f + 4.f * t_f * t_f));
    float coef = (t_f - 1.f) * __builtin_amdgcn_rcpf(tn);
    ye = w0 + coef * (w0 - wpe);
    yo = w1 + coef * (w1 - wpo);
    wpe = w0; wpo = w1;
    t_f = tn;
  }

  v2f wv = { wpe, wpo };
  ((v2f*)out)[(size_t)b * 64 + lane] = wv;   // 8B coalesced store
}

extern "C" void kernel_launch(void* const* d_in, const int* in_sizes, int n_in,
                              void* d_out, int out_size, void* d_ws, size_t ws_size,
                              hipStream_t stream) {
  (void)n_in; (void)d_ws; (void)ws_size; (void)out_size;
  const float* rets = (const float*)d_in[0];
  const float* cov  = (const float*)d_in[1];
  const float* gam  = (const float*)d_in[2];
  const float* alp  = (const float*)d_in[3];
  float* out = (float*)d_out;
  const int B = in_sizes[0] / NN;   // 1024 waves, one sample each
  markowitz_kernel<<<B, 64, 0, stream>>>(rets, cov, gam, alp, out);
}